// Round 2
// baseline (92.615 us; speedup 1.0000x reference)
//
#include <hip/hip_runtime.h>

#define NP 64          // z_vals per ray
#define NS 64          // N_importance (fixed by problem)
#define M  62          // w_mid count = NP - 2
#define NB 63          // bins (z_mid) count = NP - 1
#define RPB 4          // rays per block (one wave each)

// Wave-local LDS fence: all LDS traffic is intra-wave (each wave has its own
// slot), so lgkmcnt(0) makes this wave's ds_writes visible to its own lanes
// without the vmcnt-drain + cross-wave convergence of __syncthreads().
__device__ __forceinline__ void wave_lds_fence() {
    asm volatile("s_waitcnt lgkmcnt(0)" ::: "memory");
}

__global__ __launch_bounds__(256, 8) void nerf_fine_kernel(
    const float* __restrict__ rays_o,
    const float* __restrict__ rays_d,
    const float* __restrict__ weights,
    const float* __restrict__ z_vals,
    float* __restrict__ pts,        // [N,128,3]
    float* __restrict__ z_all_out,  // [N,128]
    int N)
{
    __shared__ float s_bins[RPB][NB];
    __shared__ float s_cdf[RPB][NB];
    __shared__ float s_zval[RPB][NP];
    __shared__ float s_zsamp[RPB][NS];
    __shared__ __align__(16) float s_zall[RPB][NP + NS];   // 512 B/wave stride, f4-aligned

    const int lane = threadIdx.x & 63;
    const int w    = threadIdx.x >> 6;
    const int ray  = blockIdx.x * RPB + w;
    if (ray >= N) return;

    // ---- prefetch ray origin/direction NOW (only used in epilogue; with no
    // barriers in between, these stay in flight under all the compute) ----
    const float rd0 = rays_d[(size_t)ray * 3 + 0];
    const float rd1 = rays_d[(size_t)ray * 3 + 1];
    const float rd2 = rays_d[(size_t)ray * 3 + 2];
    const float ro0 = rays_o[(size_t)ray * 3 + 0];
    const float ro1 = rays_o[(size_t)ray * 3 + 1];
    const float ro2 = rays_o[(size_t)ray * 3 + 2];

    // ---- coalesced per-ray loads ----
    const float zv = z_vals[(size_t)ray * NP + lane];
    const float wt = weights[(size_t)ray * NP + lane];
    s_zval[w][lane] = zv;

    // z_mid[l] = 0.5*(z[l]+z[l+1])
    const float znext = __shfl_down(zv, 1);
    if (lane < NB) s_bins[w][lane] = 0.5f * (zv + znext);

    // w_mid[l] = weights[l+1] + EPS_W, then wave inclusive scan (6 shuffles)
    const float wnext = __shfl_down(wt, 1);
    float v = (lane < M) ? (wnext + 1e-5f) : 0.0f;
    #pragma unroll
    for (int off = 1; off < 64; off <<= 1) {
        float t = __shfl_up(v, off);
        if (lane >= off) v += t;
    }
    const float rtot = __builtin_amdgcn_rcpf(__shfl(v, 63));  // v_rcp_f32, 1 ulp
    if (lane == 63) s_cdf[w][0] = 0.0f;
    if (lane < M)   s_cdf[w][lane + 1] = v * rtot;            // cdf[1..62]
    wave_lds_fence();

    // ---- inverse-CDF: u=lane/63, searchsorted side='right' over cdf[0..61] ----
    const float u = (float)lane * (1.0f / 63.0f);
    int lo = 0, hi = M;
    while (lo < hi) {
        int mid = (lo + hi) >> 1;
        if (s_cdf[w][mid] <= u) lo = mid + 1; else hi = mid;
    }
    const int above = lo;                  // [1,62]
    const int below = above - 1;
    const float cb = s_cdf[w][below], ca = s_cdf[w][above];
    const float bb = s_bins[w][below], ba = s_bins[w][above];
    float denom = ca - cb;
    if (denom < 1e-5f) denom = 1.0f;
    const float t  = (u - cb) * __builtin_amdgcn_rcpf(denom);
    const float zs = bb + t * (ba - bb);   // sorted across lanes (u inc., CDF monotone)
    s_zsamp[w][lane] = zs;
    wave_lds_fence();

    // ---- stable merge of two sorted 64-arrays via ranks ----
    {   // pos(zv) = lane + #{ zsamp < zv }
        int l2 = 0, h2 = NS;
        while (l2 < h2) { int mid = (l2 + h2) >> 1; if (s_zsamp[w][mid] < zv) l2 = mid + 1; else h2 = mid; }
        s_zall[w][lane + l2] = zv;
    }
    {   // pos(zs) = lane + #{ zval <= zs }
        int l2 = 0, h2 = NP;
        while (l2 < h2) { int mid = (l2 + h2) >> 1; if (s_zval[w][mid] <= zs) l2 = mid + 1; else h2 = mid; }
        s_zall[w][lane + l2] = zs;
    }
    wave_lds_fence();

    // ---- vectorized epilogue: 2 dwordx4 stores per lane ----
    const float* za = &s_zall[w][0];
    float4* pts4 = (float4*)(pts + (size_t)ray * 384);       // 96 float4/ray

    auto make_pt4 = [&](int j) {                             // f4 covering floats 4j..4j+3
        float4 r;
        #pragma unroll
        for (int jj = 0; jj < 4; ++jj) {
            const int id = 4 * j + jj;
            const int k  = id / 3;                           // magic-mul
            const int c  = id - 3 * k;
            const float rdc = (c == 0) ? rd0 : ((c == 1) ? rd1 : rd2);
            const float roc = (c == 0) ? ro0 : ((c == 1) ? ro1 : ro2);
            (&r.x)[jj] = fmaf(za[k], rdc, roc);
        }
        return r;
    };

    pts4[lane] = make_pt4(lane);                             // f4 0..63
    if (lane < 32) {
        pts4[64 + lane] = make_pt4(64 + lane);               // f4 64..95
    } else {
        const float4 zq = ((const float4*)za)[lane - 32];    // ds_read_b128
        ((float4*)(z_all_out + (size_t)ray * 128))[lane - 32] = zq;
    }
}

extern "C" void kernel_launch(void* const* d_in, const int* in_sizes, int n_in,
                              void* d_out, int out_size, void* d_ws, size_t ws_size,
                              hipStream_t stream) {
    const float* rays_o  = (const float*)d_in[0];
    const float* rays_d  = (const float*)d_in[1];
    const float* weights = (const float*)d_in[2];
    const float* z_vals  = (const float*)d_in[3];

    const int N = in_sizes[2] / NP;                          // weights is [N, 64]
    float* pts   = (float*)d_out;                            // [N,128,3]
    float* z_all = (float*)d_out + (size_t)N * 128 * 3;      // [N,128]

    const int blocks = (N + RPB - 1) / RPB;
    nerf_fine_kernel<<<blocks, 256, 0, stream>>>(rays_o, rays_d, weights, z_vals,
                                                 pts, z_all, N);
}

// Round 3
// 80.968 us; speedup vs baseline: 1.1439x; 1.1439x over previous
//
#include <hip/hip_runtime.h>

#define NP 64          // z_vals per ray
#define NS 64          // N_importance (fixed by problem)
#define M  62          // w_mid count = NP - 2
#define NB 63          // bins (z_mid) count = NP - 1
#define RPB 4          // rays per block (one wave each)

// Wave-local LDS fence: all LDS traffic is intra-wave (each wave has its own
// slot), so lgkmcnt(0) makes this wave's ds_writes visible to its own lanes
// without the vmcnt-drain + cross-wave convergence of __syncthreads().
__device__ __forceinline__ void wave_lds_fence() {
    asm volatile("s_waitcnt lgkmcnt(0)" ::: "memory");
}

// NOTE: no min-waves arg — R2's (256,8) capped VGPRs at 64 and spilled
// (WRITE_SIZE 134->226 MB of scratch writebacks, 2.4x slowdown).
__global__ __launch_bounds__(256) void nerf_fine_kernel(
    const float* __restrict__ rays_o,
    const float* __restrict__ rays_d,
    const float* __restrict__ weights,
    const float* __restrict__ z_vals,
    float* __restrict__ pts,        // [N,128,3]
    float* __restrict__ z_all_out,  // [N,128]
    int N)
{
    __shared__ float s_bins[RPB][NB];
    __shared__ float s_cdf[RPB][NB];
    __shared__ float s_zval[RPB][NP];
    __shared__ float s_zsamp[RPB][NS];
    __shared__ __align__(16) float s_zall[RPB][NP + NS];   // 512 B/wave, f4-aligned

    const int lane = threadIdx.x & 63;
    const int w    = threadIdx.x >> 6;
    const int ray  = blockIdx.x * RPB + w;
    if (ray >= N) return;

    // ---- prefetch ray origin/direction (used only in epilogue; no barriers
    // in between, so these stay in flight under all the compute) ----
    const float rd0 = rays_d[(size_t)ray * 3 + 0];
    const float rd1 = rays_d[(size_t)ray * 3 + 1];
    const float rd2 = rays_d[(size_t)ray * 3 + 2];
    const float ro0 = rays_o[(size_t)ray * 3 + 0];
    const float ro1 = rays_o[(size_t)ray * 3 + 1];
    const float ro2 = rays_o[(size_t)ray * 3 + 2];

    // ---- coalesced per-ray loads ----
    const float zv = z_vals[(size_t)ray * NP + lane];
    const float wt = weights[(size_t)ray * NP + lane];
    s_zval[w][lane] = zv;

    // z_mid[l] = 0.5*(z[l]+z[l+1])
    const float znext = __shfl_down(zv, 1);
    if (lane < NB) s_bins[w][lane] = 0.5f * (zv + znext);

    // w_mid[l] = weights[l+1] + EPS_W, then wave inclusive scan (6 shuffles)
    const float wnext = __shfl_down(wt, 1);
    float v = (lane < M) ? (wnext + 1e-5f) : 0.0f;
    #pragma unroll
    for (int off = 1; off < 64; off <<= 1) {
        float t = __shfl_up(v, off);
        if (lane >= off) v += t;
    }
    const float rtot = __builtin_amdgcn_rcpf(__shfl(v, 63));  // v_rcp_f32, 1 ulp
    if (lane == 63) s_cdf[w][0] = 0.0f;
    if (lane < M)   s_cdf[w][lane + 1] = v * rtot;            // cdf[1..62]
    wave_lds_fence();

    // ---- inverse-CDF: u=lane/63, searchsorted side='right' over cdf[0..61] ----
    const float u = (float)lane * (1.0f / 63.0f);
    int lo = 0, hi = M;
    while (lo < hi) {
        int mid = (lo + hi) >> 1;
        if (s_cdf[w][mid] <= u) lo = mid + 1; else hi = mid;
    }
    const int above = lo;                  // [1,62]
    const int below = above - 1;
    const float cb = s_cdf[w][below], ca = s_cdf[w][above];
    const float bb = s_bins[w][below], ba = s_bins[w][above];
    float denom = ca - cb;
    if (denom < 1e-5f) denom = 1.0f;
    const float t  = (u - cb) * __builtin_amdgcn_rcpf(denom);
    const float zs = bb + t * (ba - bb);   // sorted across lanes (u inc., CDF monotone)
    s_zsamp[w][lane] = zs;
    wave_lds_fence();

    // ---- stable merge of two sorted 64-arrays via ranks ----
    {   // pos(zv) = lane + #{ zsamp < zv }
        int l2 = 0, h2 = NS;
        while (l2 < h2) { int mid = (l2 + h2) >> 1; if (s_zsamp[w][mid] < zv) l2 = mid + 1; else h2 = mid; }
        s_zall[w][lane + l2] = zv;
    }
    {   // pos(zs) = lane + #{ zval <= zs }
        int l2 = 0, h2 = NP;
        while (l2 < h2) { int mid = (l2 + h2) >> 1; if (s_zval[w][mid] <= zs) l2 = mid + 1; else h2 = mid; }
        s_zall[w][lane + l2] = zs;
    }
    wave_lds_fence();

    // ---- vectorized epilogue: 2 dwordx4 stores per lane ----
    const float* za = &s_zall[w][0];
    float4* pts4 = (float4*)(pts + (size_t)ray * 384);       // 96 float4/ray

    auto make_pt4 = [&](int j) {                             // f4 covering floats 4j..4j+3
        float4 r;
        #pragma unroll
        for (int jj = 0; jj < 4; ++jj) {
            const int id = 4 * j + jj;
            const int k  = id / 3;                           // magic-mul
            const int c  = id - 3 * k;
            const float rdc = (c == 0) ? rd0 : ((c == 1) ? rd1 : rd2);
            const float roc = (c == 0) ? ro0 : ((c == 1) ? ro1 : ro2);
            (&r.x)[jj] = fmaf(za[k], rdc, roc);
        }
        return r;
    };

    pts4[lane] = make_pt4(lane);                             // f4 0..63
    if (lane < 32) {
        pts4[64 + lane] = make_pt4(64 + lane);               // f4 64..95
    } else {
        const float4 zq = ((const float4*)za)[lane - 32];    // ds_read_b128
        ((float4*)(z_all_out + (size_t)ray * 128))[lane - 32] = zq;
    }
}

extern "C" void kernel_launch(void* const* d_in, const int* in_sizes, int n_in,
                              void* d_out, int out_size, void* d_ws, size_t ws_size,
                              hipStream_t stream) {
    const float* rays_o  = (const float*)d_in[0];
    const float* rays_d  = (const float*)d_in[1];
    const float* weights = (const float*)d_in[2];
    const float* z_vals  = (const float*)d_in[3];

    const int N = in_sizes[2] / NP;                          // weights is [N, 64]
    float* pts   = (float*)d_out;                            // [N,128,3]
    float* z_all = (float*)d_out + (size_t)N * 128 * 3;      // [N,128]

    const int blocks = (N + RPB - 1) / RPB;
    nerf_fine_kernel<<<blocks, 256, 0, stream>>>(rays_o, rays_d, weights, z_vals,
                                                 pts, z_all, N);
}

// Round 4
// 40.902 us; speedup vs baseline: 2.2643x; 1.9796x over previous
//
#include <hip/hip_runtime.h>

#define NP 64          // z_vals per ray
#define NS 64          // N_importance (fixed by problem)
#define M  62          // w_mid count = NP - 2
#define NB 63          // bins (z_mid) count = NP - 1
#define RPB 4          // rays per block (one wave each)

// Wave-local LDS fence: all LDS traffic is intra-wave (each wave has its own
// slot), so lgkmcnt(0) makes this wave's ds_writes visible to its own lanes
// without the vmcnt-drain + cross-wave convergence of __syncthreads().
__device__ __forceinline__ void wave_lds_fence() {
    asm volatile("s_waitcnt lgkmcnt(0)" ::: "memory");
}

// Select component c of (a0,a1,a2) without forming an indexable aggregate
// (rule #20: runtime-indexed local arrays go to scratch -> 90 MB of HBM
// writeback in R2/R3).
__device__ __forceinline__ float sel3(int c, float a0, float a1, float a2) {
    return (c == 0) ? a0 : ((c == 1) ? a1 : a2);
}

__global__ __launch_bounds__(256) void nerf_fine_kernel(
    const float* __restrict__ rays_o,
    const float* __restrict__ rays_d,
    const float* __restrict__ weights,
    const float* __restrict__ z_vals,
    float* __restrict__ pts,        // [N,128,3]
    float* __restrict__ z_all_out,  // [N,128]
    int N)
{
    __shared__ float s_bins[RPB][NB];
    __shared__ float s_cdf[RPB][NB];
    __shared__ float s_zval[RPB][NP];
    __shared__ float s_zsamp[RPB][NS];
    __shared__ __align__(16) float s_zall[RPB][NP + NS];

    const int lane = threadIdx.x & 63;
    const int w    = threadIdx.x >> 6;
    const int ray  = blockIdx.x * RPB + w;
    if (ray >= N) return;

    // ---- prefetch ray origin/direction (epilogue-only; no barriers between,
    // so these stay in flight under all the compute) ----
    const float rd0 = rays_d[(size_t)ray * 3 + 0];
    const float rd1 = rays_d[(size_t)ray * 3 + 1];
    const float rd2 = rays_d[(size_t)ray * 3 + 2];
    const float ro0 = rays_o[(size_t)ray * 3 + 0];
    const float ro1 = rays_o[(size_t)ray * 3 + 1];
    const float ro2 = rays_o[(size_t)ray * 3 + 2];

    // ---- coalesced per-ray loads ----
    const float zv = z_vals[(size_t)ray * NP + lane];
    const float wt = weights[(size_t)ray * NP + lane];
    s_zval[w][lane] = zv;

    // z_mid[l] = 0.5*(z[l]+z[l+1])
    const float znext = __shfl_down(zv, 1);
    if (lane < NB) s_bins[w][lane] = 0.5f * (zv + znext);

    // w_mid[l] = weights[l+1] + EPS_W, then wave inclusive scan (6 shuffles)
    const float wnext = __shfl_down(wt, 1);
    float v = (lane < M) ? (wnext + 1e-5f) : 0.0f;
    #pragma unroll
    for (int off = 1; off < 64; off <<= 1) {
        float t = __shfl_up(v, off);
        if (lane >= off) v += t;
    }
    const float rtot = __builtin_amdgcn_rcpf(__shfl(v, 63));  // v_rcp_f32, 1 ulp
    if (lane == 63) s_cdf[w][0] = 0.0f;
    if (lane < M)   s_cdf[w][lane + 1] = v * rtot;            // cdf[1..62]
    wave_lds_fence();

    // ---- inverse-CDF: u=lane/63, searchsorted side='right' over cdf[0..61] ----
    const float u = (float)lane * (1.0f / 63.0f);
    int lo = 0, hi = M;
    while (lo < hi) {
        int mid = (lo + hi) >> 1;
        if (s_cdf[w][mid] <= u) lo = mid + 1; else hi = mid;
    }
    const int above = lo;                  // [1,62]
    const int below = above - 1;
    const float cb = s_cdf[w][below], ca = s_cdf[w][above];
    const float bb = s_bins[w][below], ba = s_bins[w][above];
    float denom = ca - cb;
    if (denom < 1e-5f) denom = 1.0f;
    const float t  = (u - cb) * __builtin_amdgcn_rcpf(denom);
    const float zs = bb + t * (ba - bb);   // sorted across lanes
    s_zsamp[w][lane] = zs;
    wave_lds_fence();

    // ---- stable merge of two sorted 64-arrays via ranks ----
    {   // pos(zv) = lane + #{ zsamp < zv }
        int l2 = 0, h2 = NS;
        while (l2 < h2) { int mid = (l2 + h2) >> 1; if (s_zsamp[w][mid] < zv) l2 = mid + 1; else h2 = mid; }
        s_zall[w][lane + l2] = zv;
    }
    {   // pos(zs) = lane + #{ zval <= zs }
        int l2 = 0, h2 = NP;
        while (l2 < h2) { int mid = (l2 + h2) >> 1; if (s_zval[w][mid] <= zs) l2 = mid + 1; else h2 = mid; }
        s_zall[w][lane + l2] = zs;
    }
    wave_lds_fence();

    // ---- vectorized epilogue: 2 dwordx4 stores per lane, NO local aggregates ----
    const float* za = &s_zall[w][0];
    float4* pts4 = (float4*)(pts + (size_t)ray * 384);       // 96 float4/ray

    // float4 j covers ids 4j..4j+3; each component fully static in structure.
    #define MAKE_PT4(r, j)                                                  \
    {                                                                       \
        const int b_ = 4 * (j);                                             \
        const int k0_ = (b_    ) / 3, c0_ = (b_    ) - 3 * k0_;             \
        const int k1_ = (b_ + 1) / 3, c1_ = (b_ + 1) - 3 * k1_;             \
        const int k2_ = (b_ + 2) / 3, c2_ = (b_ + 2) - 3 * k2_;             \
        const int k3_ = (b_ + 3) / 3, c3_ = (b_ + 3) - 3 * k3_;             \
        r.x = fmaf(za[k0_], sel3(c0_, rd0, rd1, rd2), sel3(c0_, ro0, ro1, ro2)); \
        r.y = fmaf(za[k1_], sel3(c1_, rd0, rd1, rd2), sel3(c1_, ro0, ro1, ro2)); \
        r.z = fmaf(za[k2_], sel3(c2_, rd0, rd1, rd2), sel3(c2_, ro0, ro1, ro2)); \
        r.w = fmaf(za[k3_], sel3(c3_, rd0, rd1, rd2), sel3(c3_, ro0, ro1, ro2)); \
    }

    float4 r0;
    MAKE_PT4(r0, lane);
    pts4[lane] = r0;                                         // f4 0..63

    if (lane < 32) {
        float4 r1;
        MAKE_PT4(r1, 64 + lane);
        pts4[64 + lane] = r1;                                // f4 64..95
    } else {
        const float4 zq = ((const float4*)za)[lane - 32];    // ds_read_b128
        ((float4*)(z_all_out + (size_t)ray * 128))[lane - 32] = zq;
    }
    #undef MAKE_PT4
}

extern "C" void kernel_launch(void* const* d_in, const int* in_sizes, int n_in,
                              void* d_out, int out_size, void* d_ws, size_t ws_size,
                              hipStream_t stream) {
    const float* rays_o  = (const float*)d_in[0];
    const float* rays_d  = (const float*)d_in[1];
    const float* weights = (const float*)d_in[2];
    const float* z_vals  = (const float*)d_in[3];

    const int N = in_sizes[2] / NP;                          // weights is [N, 64]
    float* pts   = (float*)d_out;                            // [N,128,3]
    float* z_all = (float*)d_out + (size_t)N * 128 * 3;      // [N,128]

    const int blocks = (N + RPB - 1) / RPB;
    nerf_fine_kernel<<<blocks, 256, 0, stream>>>(rays_o, rays_d, weights, z_vals,
                                                 pts, z_all, N);
}

// Round 5
// 34.635 us; speedup vs baseline: 2.6740x; 1.1809x over previous
//
#include <hip/hip_runtime.h>

#define NP 64          // z_vals per ray
#define M  62          // w_mid count = searched cdf prefix length
#define RPB 4          // rays per block (one wave each)

// Fully register/shuffle-resident implementation: zero __shared__, zero
// barriers. All cross-lane traffic is ds_bpermute/ds_swizzle (conflict-free).
__global__ __launch_bounds__(256) void nerf_fine_kernel(
    const float* __restrict__ rays_o,
    const float* __restrict__ rays_d,
    const float* __restrict__ weights,
    const float* __restrict__ z_vals,
    float* __restrict__ pts,        // [N,128,3]
    float* __restrict__ z_all_out,  // [N,128]
    int N)
{
    const int lane = threadIdx.x & 63;
    const int w    = threadIdx.x >> 6;
    const int ray  = blockIdx.x * RPB + w;
    if (ray >= N) return;

    // ---- loads (z/w coalesced 256B/wave; ray scalars broadcast-uniform) ----
    const float zv  = z_vals [(size_t)ray * NP + lane];
    const float wt  = weights[(size_t)ray * NP + lane];
    const float rd0 = rays_d[(size_t)ray * 3 + 0];
    const float rd1 = rays_d[(size_t)ray * 3 + 1];
    const float rd2 = rays_d[(size_t)ray * 3 + 2];
    const float ro0 = rays_o[(size_t)ray * 3 + 0];
    const float ro1 = rays_o[(size_t)ray * 3 + 1];
    const float ro2 = rays_o[(size_t)ray * 3 + 2];

    // bins register: binsv_l = z_mid[l] = 0.5*(z_l + z_{l+1}), valid l in [0,63)
    const float binsv = 0.5f * (zv + __shfl_down(zv, 1));

    // w_mid[l] = weights[l+1] + EPS_W (l < 62), wave inclusive scan (6 shuffles)
    float v = __shfl_down(wt, 1) + 1e-5f;
    v = (lane < M) ? v : 0.0f;
    #pragma unroll
    for (int off = 1; off < 64; off <<= 1) {
        float t = __shfl_up(v, off);
        if (lane >= off) v += t;
    }
    const float rtot = __builtin_amdgcn_rcpf(__shfl(v, 63)); // v_rcp_f32, 1 ulp
    const float cdfv = v * rtot;        // lane l holds cdf[l+1], l in [0,62]

    // ---- inverse-CDF: u = lane/63, searchsorted(cdf[0..61], u, 'right') ----
    // cdf[i] fetched from lane i-1's register; cdf[0] = 0 (always <= u).
    const float u = (float)lane * (1.0f / 63.0f);
    int lo = 0, hi = M;
    #pragma unroll
    for (int it = 0; it < 6; ++it) {                 // ceil(log2(62)) = 6
        const int mid = (lo + hi) >> 1;
        float cv = __shfl(cdfv, mid - 1);            // junk if mid==0 (masked)
        cv = (mid == 0) ? -1.0f : cv;                // cdf[0]=0 <= u: force le
        const bool le  = (cv <= u);
        const bool act = lo < hi;
        lo = (act &&  le) ? mid + 1 : lo;
        hi = (act && !le) ? mid     : hi;
    }
    const int above = lo;                            // [1,62]
    const int below = above - 1;                     // [0,61]
    const float ca = __shfl(cdfv, above - 1);        // cdf[above]
    float cb = __shfl(cdfv, below - 1);              // cdf[below]
    cb = (below == 0) ? 0.0f : cb;
    const float bb = __shfl(binsv, below);
    const float ba = __shfl(binsv, above);
    float denom = ca - cb;
    denom = (denom < 1e-5f) ? 1.0f : denom;
    const float t  = (u - cb) * __builtin_amdgcn_rcpf(denom);
    const float zs = fmaf(t, ba - bb, bb);           // sorted across lanes

    // ---- bitonic merge of two sorted 64-seqs, all in registers ----
    // s = [zv asc | rev(zs)] is bitonic; stage d=64 via xor-63, then 6 stages.
    float lov, hiv;
    {
        const float t0 = __shfl_xor(zs, 63);         // zs[63-lane]
        lov = fminf(zv, t0);
        hiv = fmaxf(zv, t0);
        #pragma unroll
        for (int d = 32; d >= 1; d >>= 1) {
            const float pl = __shfl_xor(lov, d);
            const float ph = __shfl_xor(hiv, d);
            const bool up  = (lane & d) != 0;
            lov = up ? fmaxf(lov, pl) : fminf(lov, pl);
            hiv = up ? fmaxf(hiv, ph) : fminf(hiv, ph);
        }
    }
    // lov = z_all[lane], hiv = z_all[64+lane]

    // ---- z_all: straight from registers, coalesced ----
    float* zo = z_all_out + (size_t)ray * 128;
    zo[lane]      = lov;
    zo[64 + lane] = hiv;

    // ---- pts: lane owns k = 2*lane, 2*lane+1 -> floats 6l..6l+5 ----
    // gather z_all[2l], z_all[2l+1] via bpermute (no LDS)
    const int i0 = (2 * lane)     & 63;
    const int i1 = (2 * lane + 1) & 63;
    const float gl0 = __shfl(lov, i0), gh0 = __shfl(hiv, i0);
    const float gl1 = __shfl(lov, i1), gh1 = __shfl(hiv, i1);
    const float zA = (lane < 32) ? gl0 : gh0;
    const float zB = (lane < 32) ? gl1 : gh1;

    // fixed component pattern c = (0,1,2,0,1,2) -> no divides, no selects
    float2* p2 = (float2*)(pts + (size_t)ray * 384 + 6 * lane);  // 24l: 8B-aligned
    float2 q0, q1, q2;
    q0.x = fmaf(zA, rd0, ro0);  q0.y = fmaf(zA, rd1, ro1);
    q1.x = fmaf(zA, rd2, ro2);  q1.y = fmaf(zB, rd0, ro0);
    q2.x = fmaf(zB, rd1, ro1);  q2.y = fmaf(zB, rd2, ro2);
    p2[0] = q0;
    p2[1] = q1;
    p2[2] = q2;
}

extern "C" void kernel_launch(void* const* d_in, const int* in_sizes, int n_in,
                              void* d_out, int out_size, void* d_ws, size_t ws_size,
                              hipStream_t stream) {
    const float* rays_o  = (const float*)d_in[0];
    const float* rays_d  = (const float*)d_in[1];
    const float* weights = (const float*)d_in[2];
    const float* z_vals  = (const float*)d_in[3];

    const int N = in_sizes[2] / NP;                      // weights is [N, 64]
    float* pts   = (float*)d_out;                        // [N,128,3]
    float* z_all = (float*)d_out + (size_t)N * 128 * 3;  // [N,128]

    const int blocks = (N + RPB - 1) / RPB;
    nerf_fine_kernel<<<blocks, 256, 0, stream>>>(rays_o, rays_d, weights, z_vals,
                                                 pts, z_all, N);
}